// Round 1
// 144.732 us; speedup vs baseline: 1.0108x; 1.0108x over previous
//
#include <hip/hip_runtime.h>

#define LN_EPS 1e-5f
#define D 768
#define D4 192          // D/4
#define TWO_D 1536

typedef float f4 __attribute__((ext_vector_type(4)));

// Single fully-fused kernel (setup_kernel eliminated, ws unused).
//
// Per-wave recompute of the 4 gate constants from the parameter vectors:
//   C_k = sum(gamma * w_k)          (for the -mean*C_k logit term)
//   E_k = sum(beta  * w_k) + gb_k   (constant logit offset)
// Each wave's 6-iteration loop already covers all 1536 columns, so the
// constants fold into the same loop and the same butterfly (12 chains).
// Parameter loads (gamma/beta/w0/w1 = 24 KB total) are L1-resident after
// the first wave per CU; the kernel stays HBM-bound on seq/msa/out.
//
// Logits: l_k = rstd*(A_k - mean*C_k) + E_k,  A_k = sum h*gamma*w_k.
// Softmax via one exp: w0 = 1/(1+exp(l1-l0)), inf-safe.
__global__ __launch_bounds__(256, 2) void fused_gate_kernel(
    const float* __restrict__ seq, const float* __restrict__ msa,
    const float* __restrict__ gamma, const float* __restrict__ beta,
    const float* __restrict__ gate_w, const float* __restrict__ gate_b,
    float* __restrict__ out, int nrows)
{
    const int wave = threadIdx.x >> 6;
    const int lane = threadIdx.x & 63;
    const int r0 = (blockIdx.x * 4 + wave) * 2;
    if (r0 >= nrows) return;
    const bool has1 = (r0 + 1) < nrows;
    const int r1 = has1 ? (r0 + 1) : r0;

    const f4* s0p = (const f4*)(seq + (size_t)r0 * D);
    const f4* m0p = (const f4*)(msa + (size_t)r0 * D);
    const f4* s1p = (const f4*)(seq + (size_t)r1 * D);
    const f4* m1p = (const f4*)(msa + (size_t)r1 * D);
    const f4* g4  = (const f4*)gamma;
    const f4* b4  = (const f4*)beta;
    const f4* w04 = (const f4*)gate_w;
    const f4* w14 = (const f4*)(gate_w + TWO_D);

    // ---- issue ALL streaming loads before any arithmetic (max MLP) ----
    // nontemporal: every seq/msa element is touched exactly once kernel-wide.
    f4 s0[3], m0[3], s1[3], m1[3];
    #pragma unroll
    for (int j = 0; j < 3; ++j) s0[j] = __builtin_nontemporal_load(&s0p[j * 64 + lane]);
    #pragma unroll
    for (int j = 0; j < 3; ++j) m0[j] = __builtin_nontemporal_load(&m0p[j * 64 + lane]);
    #pragma unroll
    for (int j = 0; j < 3; ++j) s1[j] = __builtin_nontemporal_load(&s1p[j * 64 + lane]);
    #pragma unroll
    for (int j = 0; j < 3; ++j) m1[j] = __builtin_nontemporal_load(&m1p[j * 64 + lane]);

    const float gb0 = gate_b[0];   // wave-uniform scalar loads
    const float gb1 = gate_b[1];

    // ---- fused single pass: rows 0/1 share p0/p1; constants ride along ----
    float su0 = 0.f, sq0 = 0.f, a00 = 0.f, a01 = 0.f;
    float su1 = 0.f, sq1 = 0.f, a10 = 0.f, a11 = 0.f;
    float C0 = 0.f, C1 = 0.f, E0 = 0.f, E1 = 0.f;
    #pragma unroll
    for (int j = 0; j < 6; ++j) {
        const int idx = (j < 3) ? (j * 64 + lane) : (D4 + (j - 3) * 64 + lane);
        const f4 g  = g4[idx];     // L1-hit after warmup
        const f4 w0 = w04[idx];
        const f4 w1 = w14[idx];
        const f4 bb = b4[idx];
        const f4 p0 = g * w0;
        const f4 p1 = g * w1;
        C0 += p0.x + p0.y + p0.z + p0.w;
        C1 += p1.x + p1.y + p1.z + p1.w;
        E0 += bb.x * w0.x + bb.y * w0.y + bb.z * w0.z + bb.w * w0.w;
        E1 += bb.x * w1.x + bb.y * w1.y + bb.z * w1.z + bb.w * w1.w;

        const f4 h0 = (j < 3) ? s0[j] : m0[j - 3];
        const f4 h1 = (j < 3) ? s1[j] : m1[j - 3];
        su0 += h0.x + h0.y + h0.z + h0.w;
        sq0 += h0.x * h0.x + h0.y * h0.y + h0.z * h0.z + h0.w * h0.w;
        a00 += h0.x * p0.x + h0.y * p0.y + h0.z * p0.z + h0.w * p0.w;
        a01 += h0.x * p1.x + h0.y * p1.y + h0.z * p1.z + h0.w * p1.w;
        su1 += h1.x + h1.y + h1.z + h1.w;
        sq1 += h1.x * h1.x + h1.y * h1.y + h1.z * h1.z + h1.w * h1.w;
        a10 += h1.x * p0.x + h1.y * p0.y + h1.z * p0.z + h1.w * p0.w;
        a11 += h1.x * p1.x + h1.y * p1.y + h1.z * p1.z + h1.w * p1.w;
    }

    // ---- one butterfly round, 12 independent chains ----
    #pragma unroll
    for (int off = 32; off > 0; off >>= 1) {
        su0 += __shfl_xor(su0, off, 64);
        sq0 += __shfl_xor(sq0, off, 64);
        a00 += __shfl_xor(a00, off, 64);
        a01 += __shfl_xor(a01, off, 64);
        su1 += __shfl_xor(su1, off, 64);
        sq1 += __shfl_xor(sq1, off, 64);
        a10 += __shfl_xor(a10, off, 64);
        a11 += __shfl_xor(a11, off, 64);
        C0  += __shfl_xor(C0,  off, 64);
        C1  += __shfl_xor(C1,  off, 64);
        E0  += __shfl_xor(E0,  off, 64);
        E1  += __shfl_xor(E1,  off, 64);
    }

    const float inv_n = 1.f / (float)TWO_D;
    const float e0c = E0 + gb0;
    const float e1c = E1 + gb1;

    // ---- epilogue row 0 ----
    {
        const float mean = su0 * inv_n;
        const float var  = fmaxf(sq0 * inv_n - mean * mean, 0.f);
        const float rstd = rsqrtf(var + LN_EPS);
        const float l0 = rstd * (a00 - mean * C0) + e0c;
        const float l1 = rstd * (a01 - mean * C1) + e1c;
        const float t  = __expf(l1 - l0);           // inf-safe single-exp softmax
        const float w0s = 1.f / (1.f + t);
        const float w1s = 1.f - w0s;
        f4* o4 = (f4*)(out + (size_t)r0 * D);
        #pragma unroll
        for (int j = 0; j < 3; ++j) {
            f4 o = w0s * s0[j] + w1s * m0[j];
            __builtin_nontemporal_store(o, &o4[j * 64 + lane]);
        }
    }
    // ---- epilogue row 1 ----
    if (has1) {
        const float mean = su1 * inv_n;
        const float var  = fmaxf(sq1 * inv_n - mean * mean, 0.f);
        const float rstd = rsqrtf(var + LN_EPS);
        const float l0 = rstd * (a10 - mean * C0) + e0c;
        const float l1 = rstd * (a11 - mean * C1) + e1c;
        const float t  = __expf(l1 - l0);
        const float w0s = 1.f / (1.f + t);
        const float w1s = 1.f - w0s;
        f4* o4 = (f4*)(out + (size_t)r1 * D);
        #pragma unroll
        for (int j = 0; j < 3; ++j) {
            f4 o = w0s * s1[j] + w1s * m1[j];
            __builtin_nontemporal_store(o, &o4[j * 64 + lane]);
        }
    }
}

extern "C" void kernel_launch(void* const* d_in, const int* in_sizes, int n_in,
                              void* d_out, int out_size, void* d_ws, size_t ws_size,
                              hipStream_t stream) {
    const float* seq    = (const float*)d_in[0];
    const float* msa    = (const float*)d_in[1];
    const float* gamma  = (const float*)d_in[2];
    const float* beta   = (const float*)d_in[3];
    const float* gate_w = (const float*)d_in[4];
    const float* gate_b = (const float*)d_in[5];
    float* out = (float*)d_out;
    (void)d_ws; (void)ws_size;

    const int nrows = in_sizes[0] / D;              // 16384
    const int blocks = (nrows + 7) / 8;             // 8 rows per block (2/wave)
    fused_gate_kernel<<<blocks, 256, 0, stream>>>(seq, msa, gamma, beta,
                                                  gate_w, gate_b, out, nrows);
}